// Round 8
// baseline (54.954 us; speedup 1.0000x reference)
//
#include <hip/hip_runtime.h>
#include <hip/hip_bf16.h>

typedef __attribute__((ext_vector_type(8))) short bf16x8;
typedef __attribute__((ext_vector_type(4))) float f32x4;
typedef __attribute__((ext_vector_type(2))) float f32x2;

constexpr int P = 8192, C = 8192, D = 256;
constexpr int BM = 128;     // block rows = 4 waves x 32
constexpr int BNT = 32;     // cols per N-tile
constexpr int NT = 16;      // tiles per block -> 512 cols

__device__ __forceinline__ void gload_lds16(const void* g, void* l) {
    __builtin_amdgcn_global_load_lds((const __attribute__((address_space(1))) void*)g,
                                     (__attribute__((address_space(3))) void*)l, 16, 0, 0);
}

__device__ __forceinline__ unsigned short bfbits(float f) {
    __hip_bfloat16 h = __float2bfloat16(f);
    return __builtin_bit_cast(unsigned short, h);
}

// Normalize rows to unit L2 norm, store bf16. One wave per row, float4 loads.
__global__ __launch_bounds__(256) void prep_kernel(const float* __restrict__ prev,
                                                   const float* __restrict__ cur,
                                                   unsigned short* __restrict__ prevb,
                                                   unsigned short* __restrict__ curb) {
    const int lane = threadIdx.x & 63;
    const int wv = threadIdx.x >> 6;
    const int row = blockIdx.x * 4 + wv;
    const float* src;
    unsigned short* dst;
    int r;
    if (row < P) { src = prev; dst = prevb; r = row; }
    else         { src = cur;  dst = curb;  r = row - P; }
    const float4 v = *(const float4*)(src + (size_t)r * D + lane * 4);
    float ss = v.x * v.x + v.y * v.y + v.z * v.z + v.w * v.w;
#pragma unroll
    for (int off = 32; off; off >>= 1) ss += __shfl_xor(ss, off, 64);
    const float inv = 1.0f / sqrtf(ss);   // norms ~16; eps=1e-6 unreachable
    ushort4 o;
    o.x = bfbits(v.x * inv);
    o.y = bfbits(v.y * inv);
    o.z = bfbits(v.z * inv);
    o.w = bfbits(v.w * inv);
    *(ushort4*)(dst + (size_t)r * D + lane * 4) = o;
}

// Persistent-A GEMM, ONE BARRIER PER FULL-K TILE (r7 failure: barrier every
// 8 MFMA -> cross-SIMD convoy capped MfmaUtil at 28% regardless of occupancy).
// Per interval (16 total): __syncthreads (vmcnt(0) free by construction: the
// only outstanding loads were issued a full interval ago) -> stage next
// 32x256 tile (4 x global_load_lds, double-buffered LDS) -> 32 MFMA with an
// explicit 2-deep ds_read/MFMA pipeline (no barriers inside; compiler emits
// fine-grained lgkmcnt). LDS layout [s][col][slot], slot = gsub ^ (col&7)
// (source-pre-swizzled, LDS linear) -> conflict-free ds_read_b128.
// Regs: a 64 + acc 16 + bb 16 + misc ~20 <= 128 -> 4 waves/EU, 4 blocks/CU.
__global__ __attribute__((amdgpu_flat_work_group_size(256, 256), amdgpu_waves_per_eu(4, 4)))
void gemm_bce_kernel(
    const unsigned short* __restrict__ Ab, const unsigned short* __restrict__ Bb,
    const int* __restrict__ pids, const int* __restrict__ cids,
    float* __restrict__ partial) {
    __shared__ short sB[2][BNT * 256];  // 2 x 16 KB (full-K tile buffers)
    __shared__ int cid_lds[BNT * NT];   // 2 KB
    __shared__ float wsum[4];

    const int tid = threadIdx.x;
    const int lane = tid & 63;
    const int wv = tid >> 6;
    const int pblock = blockIdx.y * BM;
    const int cbase = blockIdx.x * (BNT * NT);
    const int phase = blockIdx.y & 15;

    // ---- tile staging: thread t owns col=t>>3, phys slot p=t&7; source
    // granule gsrc = p ^ (col&7) (inverse swizzle); LDS written linearly.
    // 4 gloads cover k = s*64 .. s*64+63 (granules of 8 bf16). ----
    const int scol = tid >> 3;
    const int sgsrc = (tid & 7) ^ (scol & 7);
    auto stageTile = [&](int buf, int tl) {
        const unsigned short* src = Bb + (size_t)(cbase + tl * BNT + scol) * D + sgsrc * 8;
        short* dst = &sB[buf][0] + (size_t)tid * 8;
#pragma unroll
        for (int s = 0; s < 4; ++s)
            gload_lds16(src + s * 64, dst + s * 2048);
    };

    stageTile(0, phase);

    // ---- prologue loads (latency overlapped with tile-0 staging) ----
    const int kg = (lane >> 4) * 8;
    const int arow0 = pblock + wv * 32 + (lane & 15);
    bf16x8 a[2][8];                       // full-K A slab: 64 regs
#pragma unroll
    for (int m = 0; m < 2; ++m)
#pragma unroll
        for (int kk = 0; kk < 8; ++kk)
            a[m][kk] = *(const bf16x8*)(Ab + (size_t)(arow0 + m * 16) * D + kk * 32 + kg);

    int pidp[4];                          // pids packed 2/VGPR (ids < 16384)
#pragma unroll
    for (int m = 0; m < 2; ++m)
#pragma unroll
        for (int rp = 0; rp < 2; ++rp) {
            const int base = pblock + wv * 32 + m * 16 + (lane >> 4) * 4 + rp * 2;
            pidp[m * 2 + rp] = (pids[base] & 0xffff) | (pids[base + 1] << 16);
        }

    *(int2*)&cid_lds[tid * 2] = *(const int2*)&cids[cbase + tid * 2];

    // ---- fragment-read addressing (matches stage swizzle) ----
    // frag (kk,j): col=j*16+(lane&15); byte = (kk>>1)*4096 + col*128 +
    //   (((kk&1)*4 + (lane>>4)) ^ (lane&7)) * 16
    const int rcol = lane & 15;
    const int rx = lane >> 4;             // 0..3
    const int rswz = lane & 7;

    // ln(2cosh(x/2)) - ln2 = t/8 - t^2/192 + t^3/2880 - 17t^4/645120, t=x^2
    constexpr float C1 = 0.125f, C2 = -5.2083333e-3f, C3 = 3.4722222e-4f, C4 = -2.6354832e-5f;
    f32x2 sh2 = {0.f, 0.f}, sx2 = {0.f, 0.f};

    int buf = 0;
    for (int tt = 0; tt < NT; ++tt) {
        const int tl = (tt + phase) & 15;
        __syncthreads();   // vmcnt(0)+lgkm(0)+barrier; outstanding loads already landed
        if (tt < NT - 1) stageTile(buf ^ 1, (tt + 1 + phase) & 15);

        const char* sb = (const char*)&sB[buf][0];
        auto rdB = [&](int kk, int j) -> bf16x8 {
            return *(const bf16x8*)(sb + (kk >> 1) * 4096 + (j * 16 + rcol) * 128
                                    + ((((kk & 1) * 4 + rx) ^ rswz) << 4));
        };

        f32x4 acc[2][2] = {};
        bf16x8 bb[2][2];
        bb[0][0] = rdB(0, 0);
        bb[0][1] = rdB(0, 1);
#pragma unroll
        for (int kk = 0; kk < 8; ++kk) {
            const int cb = kk & 1;        // static after unroll
            if (kk < 7) {
                bb[cb ^ 1][0] = rdB(kk + 1, 0);
                bb[cb ^ 1][1] = rdB(kk + 1, 1);
            }
#pragma unroll
            for (int m = 0; m < 2; ++m)
#pragma unroll
                for (int j = 0; j < 2; ++j)
                    acc[m][j] = __builtin_amdgcn_mfma_f32_16x16x32_bf16(
                        a[m][kk], bb[cb][j], acc[m][j], 0, 0, 0);
        }

        // Per-tile fused BCE epilogue (VALU + LDS only; no barrier).
        // C/D layout: col=lane&15, row=(lane>>4)*4+reg (m89-verified).
        int cid_r[2];
#pragma unroll
        for (int j = 0; j < 2; ++j)
            cid_r[j] = cid_lds[tl * BNT + j * 16 + rcol];
#pragma unroll
        for (int m = 0; m < 2; ++m)
#pragma unroll
            for (int j = 0; j < 2; ++j)
#pragma unroll
                for (int rp = 0; rp < 2; ++rp) {
                    const f32x2 x = {acc[m][j][rp * 2], acc[m][j][rp * 2 + 1]};
                    const f32x2 t2 = x * x;
                    f32x2 q = t2 * C4 + C3;
                    q = t2 * q + C2;
                    q = t2 * q + C1;
                    sh2 = t2 * q + sh2;
                    const int pp = pidp[m * 2 + rp];
                    const f32x2 cc = {
                        ((pp & 0xffff) == cid_r[j]) ? -0.5f : 0.5f,
                        ((pp >> 16)    == cid_r[j]) ? -0.5f : 0.5f};
                    sx2 = x * cc + sx2;
                }
        buf ^= 1;
    }

    float lsum = sh2.x + sh2.y + sx2.x + sx2.y;
#pragma unroll
    for (int off = 32; off; off >>= 1) lsum += __shfl_xor(lsum, off, 64);
    if (lane == 0) wsum[wv] = lsum;
    __syncthreads();
    if (tid == 0) partial[blockIdx.y * gridDim.x + blockIdx.x] = wsum[0] + wsum[1] + wsum[2] + wsum[3];
}

// Deterministic final reduction over 1024 block partials; adds folded ln2.
__global__ __launch_bounds__(256) void reduce_kernel(const float* __restrict__ part,
                                                     float* __restrict__ out) {
    const int tid = threadIdx.x;
    double s = 0.0;
    for (int i = tid; i < 1024; i += 256) s += (double)part[i];
#pragma unroll
    for (int off = 32; off; off >>= 1) s += __shfl_xor(s, off, 64);
    __shared__ double red[4];
    const int lane = tid & 63, wv = tid >> 6;
    if (lane == 0) red[wv] = s;
    __syncthreads();
    if (tid == 0)
        out[0] = (float)((red[0] + red[1] + red[2] + red[3]) * (1.0 / ((double)P * (double)C))
                         + 0.69314718055994531);
}

extern "C" void kernel_launch(void* const* d_in, const int* in_sizes, int n_in,
                              void* d_out, int out_size, void* d_ws, size_t ws_size,
                              hipStream_t stream) {
    const float* prev_feat = (const float*)d_in[0];
    const float* cur_feat  = (const float*)d_in[1];
    const int* prev_ids    = (const int*)d_in[2];
    const int* cur_ids     = (const int*)d_in[3];
    float* out = (float*)d_out;

    char* ws = (char*)d_ws;
    unsigned short* prevb = (unsigned short*)ws;                          // 4 MB
    unsigned short* curb  = (unsigned short*)(ws + (size_t)P * D * 2);    // 4 MB
    float* partial = (float*)(ws + (size_t)(P + C) * D * 2);              // 4 KB

    prep_kernel<<<(P + C) / 4, 256, 0, stream>>>(prev_feat, cur_feat, prevb, curb);
    dim3 grid(C / (BNT * NT), P / BM);                                    // 16 x 64
    gemm_bce_kernel<<<grid, 256, 0, stream>>>(prevb, curb, prev_ids, cur_ids, partial);
    reduce_kernel<<<1, 256, 0, stream>>>(partial, out);
}